// Round 11
// baseline (305.721 us; speedup 1.0000x reference)
//
#include <hip/hip_runtime.h>
#include <hip/hip_bf16.h>
#include <math.h>

typedef __attribute__((ext_vector_type(4))) float f32x4;
typedef __attribute__((ext_vector_type(8))) int i32x8;
typedef __attribute__((ext_vector_type(4))) int i32x4;

#define BM 128
#define BN 128
#define BK 128
#define TEMP_INV 14.2857142857142857f   // 1/0.07
#define UNIT_SCALE 0x7f7f7f7f           // E8M0 127 -> x1.0 exact (R6/R7/R10-verified)

union frag32 {
  i32x8 v8;
  struct { i32x4 lo; i32x4 hi; } s;
};

// ---- async global->LDS, 16B per lane
static __device__ inline void async16(const void* g, void* l) {
  __builtin_amdgcn_global_load_lds(
      (const __attribute__((address_space(1))) unsigned int*)g,
      (__attribute__((address_space(3))) unsigned int*)l,
      16, 0, 0);
}

// ============================================================
// Kernel 1: L2-normalize rows of A and B (D=1024), emit fp8 e4m3
// (plain row-major). Also zeroes pos/neg accumulators.
// ============================================================
__global__ __launch_bounds__(256) void normalize_rows(
    const float* __restrict__ a, const float* __restrict__ b,
    unsigned char* __restrict__ oa, unsigned char* __restrict__ ob,
    float* __restrict__ pos_acc, float* __restrict__ neg_acc,
    int N, int D) {
  const int blk = blockIdx.x;
  const float* in;
  unsigned char* out;
  if (blk < N) {
    in = a + (size_t)blk * D;
    out = oa + (size_t)blk * D;
    if (threadIdx.x == 0) { pos_acc[blk] = 0.f; neg_acc[blk] = 0.f; }
  } else {
    in = b + (size_t)(blk - N) * D;
    out = ob + (size_t)(blk - N) * D;
  }
  const int t = threadIdx.x;
  const float4 v = ((const float4*)in)[t];
  float ss = v.x * v.x + v.y * v.y + v.z * v.z + v.w * v.w;
#pragma unroll
  for (int m = 32; m >= 1; m >>= 1) ss += __shfl_xor(ss, m, 64);
  __shared__ float wsum[4];
  const int wave = t >> 6, lane = t & 63;
  if (lane == 0) wsum[wave] = ss;
  __syncthreads();
  const float tot = wsum[0] + wsum[1] + wsum[2] + wsum[3];
  const float inv = 1.0f / fmaxf(sqrtf(tot), 1e-12f);
  int r = __builtin_amdgcn_cvt_pk_fp8_f32(v.x * inv, v.y * inv, 0, false);
  r = __builtin_amdgcn_cvt_pk_fp8_f32(v.z * inv, v.w * inv, r, true);
  ((int*)out)[t] = r;
}

// ============================================================
// Kernel 2: fused MX-fp8 MFMA GEMM (A[N,D] x B[M,D]^T) + exp epilogue.
// R10 winner (mfma_scale_f32_16x16x128_f8f6f4, BK=128, swizzled LDS,
// global_load_lds width-16) + DOUBLE BUFFER, one barrier per phase:
//   barrier -> STAGE(k+1, other buf) -> COMPUTE(k)
// The prefetch has the whole compute phase (16 MFMA + 16 ds_read_b128
// ~1300 cyc) to land before the barrier that drains it -> staging
// exposure ~0 (was ~900 cyc/phase fully exposed in R10's single buf).
// LDS 64 KB -> 2 blocks/CU; within-block prefetch overlap replaces the
// lost third block (m132's regression was unroll-without-prefetch).
//
// LDS slot swizzle (R10, conflicts at b128 floor): row r = 8 x 16B
// slots, logical slot s at phys s ^ (r&7).
// C/D layout (16x16, verified): col=lane&15, row=(lane>>4)*4+reg.
// ============================================================
__global__ __launch_bounds__(256, 2) void infonce_gemm(
    const unsigned char* __restrict__ A, const unsigned char* __restrict__ B,
    const int* __restrict__ la, const int* __restrict__ lb,
    float* __restrict__ pos_acc, float* __restrict__ neg_acc, int D) {
  __shared__ __align__(16) unsigned char sA[2][BM * BK];  // 2 x 16 KB
  __shared__ __align__(16) unsigned char sB[2][BN * BK];  // 2 x 16 KB

  const int tid = threadIdx.x;
  const int lane = tid & 63;
  const int wave = tid >> 6;
  const int wm = wave >> 1;  // 0..1
  const int wn = wave & 1;   // 0..1
  const int row0 = blockIdx.y * BM;
  const int col0 = blockIdx.x * BN;

  // staging: call c covers rows c*32 + (tid>>3); within-row logical 16B
  // slot l = (tid&7) ^ ((tid>>3)&7)
  const int srow = tid >> 3;
  const int sl = ((tid & 7) ^ (srow & 7)) * 16;
  const unsigned char* gA = A + (size_t)(row0 + srow) * D + sl;
  const unsigned char* gB = B + (size_t)(col0 + srow) * D + sl;

  f32x4 acc[4][4] = {};

  const int q = lane >> 4;    // 0..3
  const int l15 = lane & 15;  // 0..15
  const int phys0 = ((2 * q) ^ (l15 & 7)) * 16;  // loop-invariant

#define STAGE(bufi, kk)                                             \
  do {                                                              \
    _Pragma("unroll") for (int c = 0; c < 4; c++) {                 \
      async16(gA + (size_t)c * 32 * 1024 + (kk),                    \
              &sA[bufi][(c * 256 + tid) * 16]);                     \
      async16(gB + (size_t)c * 32 * 1024 + (kk),                    \
              &sB[bufi][(c * 256 + tid) * 16]);                     \
    }                                                               \
  } while (0)

  // lane's 32B fragment for tile-row rr: logical slots (2q, 2q+1)
#define LOAD32(dst, bufp, rr)                                   \
  do {                                                          \
    const unsigned char* _p = &(bufp)[(rr) * BK];               \
    frag32 _f;                                                  \
    _f.s.lo = *(const i32x4*)(_p + phys0);                      \
    _f.s.hi = *(const i32x4*)(_p + (phys0 ^ 16));               \
    dst = _f.v8;                                                \
  } while (0)

#define COMPUTE(bufi)                                                         \
  do {                                                                        \
    i32x8 bf0, bf1, bf2, bf3;                                                 \
    LOAD32(bf0, sB[bufi], wn * 64 + 0 + l15);                                 \
    LOAD32(bf1, sB[bufi], wn * 64 + 16 + l15);                                \
    LOAD32(bf2, sB[bufi], wn * 64 + 32 + l15);                                \
    LOAD32(bf3, sB[bufi], wn * 64 + 48 + l15);                                \
    _Pragma("unroll") for (int i = 0; i < 4; i++) {                           \
      i32x8 af;                                                               \
      LOAD32(af, sA[bufi], wm * 64 + i * 16 + l15);                           \
      acc[i][0] = __builtin_amdgcn_mfma_scale_f32_16x16x128_f8f6f4(           \
          af, bf0, acc[i][0], 0, 0, 0, UNIT_SCALE, 0, UNIT_SCALE);            \
      acc[i][1] = __builtin_amdgcn_mfma_scale_f32_16x16x128_f8f6f4(           \
          af, bf1, acc[i][1], 0, 0, 0, UNIT_SCALE, 0, UNIT_SCALE);            \
      acc[i][2] = __builtin_amdgcn_mfma_scale_f32_16x16x128_f8f6f4(           \
          af, bf2, acc[i][2], 0, 0, 0, UNIT_SCALE, 0, UNIT_SCALE);            \
      acc[i][3] = __builtin_amdgcn_mfma_scale_f32_16x16x128_f8f6f4(           \
          af, bf3, acc[i][3], 0, 0, 0, UNIT_SCALE, 0, UNIT_SCALE);            \
    }                                                                         \
  } while (0)

  STAGE(0, 0);
#pragma unroll 1
  for (int k0 = 0; k0 < D; k0 += 2 * BK) {
    __syncthreads();  // tile(k0) visible in buf0; buf1 free
    if (k0 + BK < D) STAGE(1, k0 + BK);
    COMPUTE(0);
    __syncthreads();  // tile(k0+BK) visible in buf1; buf0 reads done
    if (k0 + 2 * BK < D) STAGE(0, k0 + 2 * BK);
    COMPUTE(1);
  }

  // ---- epilogue: C/D layout col = lane&15, row = quad*4 + reg (verified)
  int lbv[4];
#pragma unroll
  for (int j = 0; j < 4; j++) lbv[j] = lb[col0 + wn * 64 + j * 16 + l15];

#pragma unroll
  for (int i = 0; i < 4; i++) {
#pragma unroll
    for (int r = 0; r < 4; r++) {
      const int row = row0 + wm * 64 + i * 16 + q * 4 + r;
      const int lav = la[row];
      float sneg = 0.f, spos = 0.f;
#pragma unroll
      for (int j = 0; j < 4; j++) {
        float s = acc[i][j][r] * TEMP_INV;
        s = fminf(fmaxf(s, -50.f), 50.f);
        const float e = __expf(s);
        sneg += e;
        if (lav == lbv[j]) spos += e;
      }
#pragma unroll
      for (int m = 8; m >= 1; m >>= 1) {
        sneg += __shfl_xor(sneg, m, 16);
        spos += __shfl_xor(spos, m, 16);
      }
      if (l15 == 0) {
        atomicAdd(&neg_acc[row], sneg);
        atomicAdd(&pos_acc[row], spos);
      }
    }
  }
}

// ============================================================
// Kernel 3: loss = mean( log(neg) - log(max(pos,1e-8)) )
// ============================================================
__global__ __launch_bounds__(1024) void final_reduce(
    const float* __restrict__ pos, const float* __restrict__ neg,
    float* __restrict__ out, int N) {
  double local = 0.0;
  const int t = threadIdx.x;
  for (int i = t; i < N / 4; i += 1024) {
    const float4 p4 = ((const float4*)pos)[i];
    const float4 n4 = ((const float4*)neg)[i];
    local += (double)(logf(n4.x) - logf(fmaxf(p4.x, 1e-8f)));
    local += (double)(logf(n4.y) - logf(fmaxf(p4.y, 1e-8f)));
    local += (double)(logf(n4.z) - logf(fmaxf(p4.z, 1e-8f)));
    local += (double)(logf(n4.w) - logf(fmaxf(p4.w, 1e-8f)));
  }
#pragma unroll
  for (int m = 32; m >= 1; m >>= 1) local += __shfl_xor(local, m, 64);
  __shared__ double wsum[16];
  const int wave = t >> 6, lane = t & 63;
  if (lane == 0) wsum[wave] = local;
  __syncthreads();
  if (t == 0) {
    double tot = 0.0;
#pragma unroll
    for (int w = 0; w < 16; w++) tot += wsum[w];
    out[0] = (float)(tot / (double)N);
  }
}

extern "C" void kernel_launch(void* const* d_in, const int* in_sizes, int n_in,
                              void* d_out, int out_size, void* d_ws, size_t ws_size,
                              hipStream_t stream) {
  const float* fa = (const float*)d_in[0];
  const float* fb = (const float*)d_in[1];
  const int* la = (const int*)d_in[2];
  const int* lb = (const int*)d_in[3];

  const int D = 1024;
  const int N = in_sizes[0] / D;  // 8192
  const int M = in_sizes[1] / D;  // 8192

  unsigned char* nA = (unsigned char*)d_ws;
  unsigned char* nB = nA + (size_t)N * D;
  float* pos = (float*)(nB + (size_t)M * D);
  float* neg = pos + N;

  normalize_rows<<<N + M, 256, 0, stream>>>(fa, fb, nA, nB, pos, neg, N, D);

  dim3 grid(M / BN, N / BM);
  infonce_gemm<<<grid, 256, 0, stream>>>(nA, nB, la, lb, pos, neg, D);

  final_reduce<<<1, 1024, 0, stream>>>(pos, neg, (float*)d_out, N);
}

// Round 12
// 278.604 us; speedup vs baseline: 1.0973x; 1.0973x over previous
//
#include <hip/hip_runtime.h>
#include <hip/hip_bf16.h>
#include <math.h>

typedef __attribute__((ext_vector_type(4))) float f32x4;
typedef __attribute__((ext_vector_type(8))) int i32x8;
typedef __attribute__((ext_vector_type(4))) int i32x4;

#define BM 128
#define BN 128
#define BK 128
#define TEMP_INV 14.2857142857142857f   // 1/0.07
#define UNIT_SCALE 0x7f7f7f7f           // E8M0 127 -> x1.0 exact (R6/R7/R10-verified)

// s_waitcnt imm (gfx9 encoding): lgkmcnt(0), vmcnt=max(63), expcnt=max(7)
#define WAIT_LGKM0 0xC07F

union frag32 {
  i32x8 v8;
  struct { i32x4 lo; i32x4 hi; } s;
};

// ============================================================
// Kernel 1: L2-normalize rows of A and B (D=1024), emit fp8 e4m3
// (plain row-major). Also zeroes pos/neg accumulators.
// ============================================================
__global__ __launch_bounds__(256) void normalize_rows(
    const float* __restrict__ a, const float* __restrict__ b,
    unsigned char* __restrict__ oa, unsigned char* __restrict__ ob,
    float* __restrict__ pos_acc, float* __restrict__ neg_acc,
    int N, int D) {
  const int blk = blockIdx.x;
  const float* in;
  unsigned char* out;
  if (blk < N) {
    in = a + (size_t)blk * D;
    out = oa + (size_t)blk * D;
    if (threadIdx.x == 0) { pos_acc[blk] = 0.f; neg_acc[blk] = 0.f; }
  } else {
    in = b + (size_t)(blk - N) * D;
    out = ob + (size_t)(blk - N) * D;
  }
  const int t = threadIdx.x;
  const float4 v = ((const float4*)in)[t];
  float ss = v.x * v.x + v.y * v.y + v.z * v.z + v.w * v.w;
#pragma unroll
  for (int m = 32; m >= 1; m >>= 1) ss += __shfl_xor(ss, m, 64);
  __shared__ float wsum[4];
  const int wave = t >> 6, lane = t & 63;
  if (lane == 0) wsum[wave] = ss;
  __syncthreads();
  const float tot = wsum[0] + wsum[1] + wsum[2] + wsum[3];
  const float inv = 1.0f / fmaxf(sqrtf(tot), 1e-12f);
  int r = __builtin_amdgcn_cvt_pk_fp8_f32(v.x * inv, v.y * inv, 0, false);
  r = __builtin_amdgcn_cvt_pk_fp8_f32(v.z * inv, v.w * inv, r, true);
  ((int*)out)[t] = r;
}

// ============================================================
// Kernel 2: fused MX-fp8 MFMA GEMM (A[N,D] x B[M,D]^T) + exp epilogue.
// R10 winner (mfma_scale_f32_16x16x128_f8f6f4, BK=128, swizzled LDS,
// 8 phases) with 1.5-STAGE transport: single 32 KB LDS buffer (keeps
// R10's 3-block/CU residency) + tile k+1 staged into VGPRs during
// COMPUTE(k) (32 VGPRs/thread), ds_write at the phase boundary.
// Phase: WRITELDS(k) -> lgkm-wait -> s_barrier -> LOADG(k+1) ->
//        COMPUTE(k) -> s_barrier(raw, no vmcnt drain).
// The only vmcnt wait is the compiler's at WRITELDS -- a full compute
// phase (~1300 cyc) after issue, so the ~900-cyc staging exposure of
// R10's serial STAGE collapses to ~4 ds_write_b128. (Transport+raw-
// barrier pattern correctness-proven in R9.)
//
// LDS slot swizzle (R10, conflicts at b128 floor): row r = 8 x 16B
// slots, logical slot s at phys s ^ (r&7).
// C/D layout (16x16, verified): col=lane&15, row=(lane>>4)*4+reg.
// ============================================================
__global__ __launch_bounds__(256, 3) void infonce_gemm(
    const unsigned char* __restrict__ A, const unsigned char* __restrict__ B,
    const int* __restrict__ la, const int* __restrict__ lb,
    float* __restrict__ pos_acc, float* __restrict__ neg_acc, int D) {
  __shared__ __align__(16) unsigned char sA[BM * BK];  // 16 KB
  __shared__ __align__(16) unsigned char sB[BN * BK];  // 16 KB

  const int tid = threadIdx.x;
  const int lane = tid & 63;
  const int wave = tid >> 6;
  const int wm = wave >> 1;  // 0..1
  const int wn = wave & 1;   // 0..1
  const int row0 = blockIdx.y * BM;
  const int col0 = blockIdx.x * BN;

  // staging: call c covers rows c*32 + (tid>>3); within-row logical 16B
  // slot l = (tid&7) ^ ((tid>>3)&7)
  const int srow = tid >> 3;
  const int sl = ((tid & 7) ^ (srow & 7)) * 16;
  const unsigned char* gA = A + (size_t)(row0 + srow) * D + sl;
  const unsigned char* gB = B + (size_t)(col0 + srow) * D + sl;

  f32x4 acc[4][4] = {};

  const int q = lane >> 4;    // 0..3
  const int l15 = lane & 15;  // 0..15
  const int phys0 = ((2 * q) ^ (l15 & 7)) * 16;  // loop-invariant

  i32x4 ra[4], rb[4];  // staging registers (in flight across barriers)

#define LOADG(kk)                                                   \
  do {                                                              \
    _Pragma("unroll") for (int c = 0; c < 4; c++) {                 \
      ra[c] = *(const i32x4*)(gA + (size_t)c * 32 * 1024 + (kk));   \
      rb[c] = *(const i32x4*)(gB + (size_t)c * 32 * 1024 + (kk));   \
    }                                                               \
  } while (0)

#define WRITELDS()                                                  \
  do {                                                              \
    _Pragma("unroll") for (int c = 0; c < 4; c++) {                 \
      *(i32x4*)&sA[(c * 256 + tid) * 16] = ra[c];                   \
      *(i32x4*)&sB[(c * 256 + tid) * 16] = rb[c];                   \
    }                                                               \
  } while (0)

  // lane's 32B fragment for tile-row rr: logical slots (2q, 2q+1)
#define LOAD32(dst, bufp, rr)                                   \
  do {                                                          \
    const unsigned char* _p = &(bufp)[(rr) * BK];               \
    frag32 _f;                                                  \
    _f.s.lo = *(const i32x4*)(_p + phys0);                      \
    _f.s.hi = *(const i32x4*)(_p + (phys0 ^ 16));               \
    dst = _f.v8;                                                \
  } while (0)

#define COMPUTE()                                                             \
  do {                                                                        \
    i32x8 bf0, bf1, bf2, bf3;                                                 \
    LOAD32(bf0, sB, wn * 64 + 0 + l15);                                       \
    LOAD32(bf1, sB, wn * 64 + 16 + l15);                                      \
    LOAD32(bf2, sB, wn * 64 + 32 + l15);                                      \
    LOAD32(bf3, sB, wn * 64 + 48 + l15);                                      \
    _Pragma("unroll") for (int i = 0; i < 4; i++) {                           \
      i32x8 af;                                                               \
      LOAD32(af, sA, wm * 64 + i * 16 + l15);                                 \
      acc[i][0] = __builtin_amdgcn_mfma_scale_f32_16x16x128_f8f6f4(           \
          af, bf0, acc[i][0], 0, 0, 0, UNIT_SCALE, 0, UNIT_SCALE);            \
      acc[i][1] = __builtin_amdgcn_mfma_scale_f32_16x16x128_f8f6f4(           \
          af, bf1, acc[i][1], 0, 0, 0, UNIT_SCALE, 0, UNIT_SCALE);            \
      acc[i][2] = __builtin_amdgcn_mfma_scale_f32_16x16x128_f8f6f4(           \
          af, bf2, acc[i][2], 0, 0, 0, UNIT_SCALE, 0, UNIT_SCALE);            \
      acc[i][3] = __builtin_amdgcn_mfma_scale_f32_16x16x128_f8f6f4(           \
          af, bf3, acc[i][3], 0, 0, 0, UNIT_SCALE, 0, UNIT_SCALE);            \
    }                                                                         \
  } while (0)

  LOADG(0);
#pragma unroll 1
  for (int k0 = 0; k0 < D; k0 += BK) {
    WRITELDS();                              // compiler waits vmcnt here
    __builtin_amdgcn_s_waitcnt(WAIT_LGKM0);  // ds_writes visible
    __builtin_amdgcn_s_barrier();            // tile k0 visible to all waves
    if (k0 + BK < D) LOADG(k0 + BK);         // in flight across compute+barrier
    COMPUTE();
    __builtin_amdgcn_s_barrier();            // all reads done (no vmcnt drain)
  }

  // ---- epilogue: C/D layout col = lane&15, row = quad*4 + reg (verified)
  int lbv[4];
#pragma unroll
  for (int j = 0; j < 4; j++) lbv[j] = lb[col0 + wn * 64 + j * 16 + l15];

#pragma unroll
  for (int i = 0; i < 4; i++) {
#pragma unroll
    for (int r = 0; r < 4; r++) {
      const int row = row0 + wm * 64 + i * 16 + q * 4 + r;
      const int lav = la[row];
      float sneg = 0.f, spos = 0.f;
#pragma unroll
      for (int j = 0; j < 4; j++) {
        float s = acc[i][j][r] * TEMP_INV;
        s = fminf(fmaxf(s, -50.f), 50.f);
        const float e = __expf(s);
        sneg += e;
        if (lav == lbv[j]) spos += e;
      }
#pragma unroll
      for (int m = 8; m >= 1; m >>= 1) {
        sneg += __shfl_xor(sneg, m, 16);
        spos += __shfl_xor(spos, m, 16);
      }
      if (l15 == 0) {
        atomicAdd(&neg_acc[row], sneg);
        atomicAdd(&pos_acc[row], spos);
      }
    }
  }
}

// ============================================================
// Kernel 3: loss = mean( log(neg) - log(max(pos,1e-8)) )
// ============================================================
__global__ __launch_bounds__(1024) void final_reduce(
    const float* __restrict__ pos, const float* __restrict__ neg,
    float* __restrict__ out, int N) {
  double local = 0.0;
  const int t = threadIdx.x;
  for (int i = t; i < N / 4; i += 1024) {
    const float4 p4 = ((const float4*)pos)[i];
    const float4 n4 = ((const float4*)neg)[i];
    local += (double)(logf(n4.x) - logf(fmaxf(p4.x, 1e-8f)));
    local += (double)(logf(n4.y) - logf(fmaxf(p4.y, 1e-8f)));
    local += (double)(logf(n4.z) - logf(fmaxf(p4.z, 1e-8f)));
    local += (double)(logf(n4.w) - logf(fmaxf(p4.w, 1e-8f)));
  }
#pragma unroll
  for (int m = 32; m >= 1; m >>= 1) local += __shfl_xor(local, m, 64);
  __shared__ double wsum[16];
  const int wave = t >> 6, lane = t & 63;
  if (lane == 0) wsum[wave] = local;
  __syncthreads();
  if (t == 0) {
    double tot = 0.0;
#pragma unroll
    for (int w = 0; w < 16; w++) tot += wsum[w];
    out[0] = (float)(tot / (double)N);
  }
}

extern "C" void kernel_launch(void* const* d_in, const int* in_sizes, int n_in,
                              void* d_out, int out_size, void* d_ws, size_t ws_size,
                              hipStream_t stream) {
  const float* fa = (const float*)d_in[0];
  const float* fb = (const float*)d_in[1];
  const int* la = (const int*)d_in[2];
  const int* lb = (const int*)d_in[3];

  const int D = 1024;
  const int N = in_sizes[0] / D;  // 8192
  const int M = in_sizes[1] / D;  // 8192

  unsigned char* nA = (unsigned char*)d_ws;
  unsigned char* nB = nA + (size_t)N * D;
  float* pos = (float*)(nB + (size_t)M * D);
  float* neg = pos + N;

  normalize_rows<<<N + M, 256, 0, stream>>>(fa, fb, nA, nB, pos, neg, N, D);

  dim3 grid(M / BN, N / BM);
  infonce_gemm<<<grid, 256, 0, stream>>>(nA, nB, la, lb, pos, neg, D);

  final_reduce<<<1, 1024, 0, stream>>>(pos, neg, (float*)d_out, N);
}

// Round 13
// 258.400 us; speedup vs baseline: 1.1831x; 1.0782x over previous
//
#include <hip/hip_runtime.h>
#include <hip/hip_bf16.h>
#include <math.h>

typedef __attribute__((ext_vector_type(4))) float f32x4;
typedef __attribute__((ext_vector_type(8))) int i32x8;
typedef __attribute__((ext_vector_type(4))) int i32x4;

#define BM 128
#define BN 128
#define BK 128
#define TEMP_INV 14.2857142857142857f   // 1/0.07
#define UNIT_SCALE 0x7f7f7f7f           // E8M0 127 -> x1.0 exact (verified)

union frag32 {
  i32x8 v8;
  struct { i32x4 lo; i32x4 hi; } s;
};

// ---- async global->LDS, 16B per lane
static __device__ inline void async16(const void* g, void* l) {
  __builtin_amdgcn_global_load_lds(
      (const __attribute__((address_space(1))) unsigned int*)g,
      (__attribute__((address_space(3))) unsigned int*)l,
      16, 0, 0);
}

// ============================================================
// Kernel 1: L2-normalize rows of A and B (D=1024), emit fp8 e4m3
// (plain row-major). Also zeroes pos/neg accumulators.
// ============================================================
__global__ __launch_bounds__(256) void normalize_rows(
    const float* __restrict__ a, const float* __restrict__ b,
    unsigned char* __restrict__ oa, unsigned char* __restrict__ ob,
    float* __restrict__ pos_acc, float* __restrict__ neg_acc,
    int N, int D) {
  const int blk = blockIdx.x;
  const float* in;
  unsigned char* out;
  if (blk < N) {
    in = a + (size_t)blk * D;
    out = oa + (size_t)blk * D;
    if (threadIdx.x == 0) { pos_acc[blk] = 0.f; neg_acc[blk] = 0.f; }
  } else {
    in = b + (size_t)(blk - N) * D;
    out = ob + (size_t)(blk - N) * D;
  }
  const int t = threadIdx.x;
  const float4 v = ((const float4*)in)[t];
  float ss = v.x * v.x + v.y * v.y + v.z * v.z + v.w * v.w;
#pragma unroll
  for (int m = 32; m >= 1; m >>= 1) ss += __shfl_xor(ss, m, 64);
  __shared__ float wsum[4];
  const int wave = t >> 6, lane = t & 63;
  if (lane == 0) wsum[wave] = ss;
  __syncthreads();
  const float tot = wsum[0] + wsum[1] + wsum[2] + wsum[3];
  const float inv = 1.0f / fmaxf(sqrtf(tot), 1e-12f);
  int r = __builtin_amdgcn_cvt_pk_fp8_f32(v.x * inv, v.y * inv, 0, false);
  r = __builtin_amdgcn_cvt_pk_fp8_f32(v.z * inv, v.w * inv, r, true);
  ((int*)out)[t] = r;
}

// ============================================================
// Kernel 2: fused MX-fp8 MFMA GEMM (A[N,D] x B[M,D]^T) + exp epilogue.
// EXACT R10 winner (mfma_scale_f32_16x16x128_f8f6f4, BK=128, single
// 32 KB LDS, m97 2-barrier skeleton, global_load_lds width-16,
// swizzled LDS at the b128 conflict floor) with ONE change:
// __launch_bounds__(256, 4) -> allocator targets <=128 unified
// regs/wave -> 4 waves/SIMD = 4 blocks/CU (LDS 4x32=128<=160 KB ok).
// Also: grid 4096 = 1024 CU-slots x 4 exactly -> no dispatch tail
// (at 3/CU the 5.3-wave quantization cost ~19%).
//
// LDS slot swizzle: row r = 8 x 16B slots, logical slot s at phys
// s ^ (r&7). C/D layout (16x16, verified): col=lane&15,
// row=(lane>>4)*4+reg.
// ============================================================
__global__ __launch_bounds__(256, 4) void infonce_gemm(
    const unsigned char* __restrict__ A, const unsigned char* __restrict__ B,
    const int* __restrict__ la, const int* __restrict__ lb,
    float* __restrict__ pos_acc, float* __restrict__ neg_acc, int D) {
  __shared__ __align__(16) unsigned char sA[BM * BK];  // 16 KB
  __shared__ __align__(16) unsigned char sB[BN * BK];  // 16 KB

  const int tid = threadIdx.x;
  const int lane = tid & 63;
  const int wave = tid >> 6;
  const int wm = wave >> 1;  // 0..1
  const int wn = wave & 1;   // 0..1
  const int row0 = blockIdx.y * BM;
  const int col0 = blockIdx.x * BN;

  // staging: call c covers rows c*32 + (tid>>3); within-row logical 16B
  // slot l = (tid&7) ^ ((tid>>3)&7)
  const int srow = tid >> 3;
  const int sl = ((tid & 7) ^ (srow & 7)) * 16;
  const unsigned char* gA = A + (size_t)(row0 + srow) * D + sl;
  const unsigned char* gB = B + (size_t)(col0 + srow) * D + sl;

  f32x4 acc[4][4] = {};

  const int q = lane >> 4;    // 0..3
  const int l15 = lane & 15;  // 0..15
  const int phys0 = ((2 * q) ^ (l15 & 7)) * 16;  // loop-invariant

#define STAGE(kk)                                                   \
  do {                                                              \
    _Pragma("unroll") for (int c = 0; c < 4; c++) {                 \
      async16(gA + (size_t)c * 32 * 1024 + (kk),                    \
              &sA[(c * 256 + tid) * 16]);                           \
      async16(gB + (size_t)c * 32 * 1024 + (kk),                    \
              &sB[(c * 256 + tid) * 16]);                           \
    }                                                               \
  } while (0)

  // lane's 32B fragment for tile-row rr: logical slots (2q, 2q+1)
#define LOAD32(dst, bufp, rr)                                   \
  do {                                                          \
    const unsigned char* _p = &(bufp)[(rr) * BK];               \
    frag32 _f;                                                  \
    _f.s.lo = *(const i32x4*)(_p + phys0);                      \
    _f.s.hi = *(const i32x4*)(_p + (phys0 ^ 16));               \
    dst = _f.v8;                                                \
  } while (0)

#pragma unroll 1
  for (int k0 = 0; k0 < D; k0 += BK) {
    STAGE(k0);
    __syncthreads();  // drain global_load_lds; tile visible
    i32x8 bf0, bf1, bf2, bf3;
    LOAD32(bf0, sB, wn * 64 + 0 + l15);
    LOAD32(bf1, sB, wn * 64 + 16 + l15);
    LOAD32(bf2, sB, wn * 64 + 32 + l15);
    LOAD32(bf3, sB, wn * 64 + 48 + l15);
#pragma unroll
    for (int i = 0; i < 4; i++) {
      i32x8 af;
      LOAD32(af, sA, wm * 64 + i * 16 + l15);
      acc[i][0] = __builtin_amdgcn_mfma_scale_f32_16x16x128_f8f6f4(
          af, bf0, acc[i][0], 0, 0, 0, UNIT_SCALE, 0, UNIT_SCALE);
      acc[i][1] = __builtin_amdgcn_mfma_scale_f32_16x16x128_f8f6f4(
          af, bf1, acc[i][1], 0, 0, 0, UNIT_SCALE, 0, UNIT_SCALE);
      acc[i][2] = __builtin_amdgcn_mfma_scale_f32_16x16x128_f8f6f4(
          af, bf2, acc[i][2], 0, 0, 0, UNIT_SCALE, 0, UNIT_SCALE);
      acc[i][3] = __builtin_amdgcn_mfma_scale_f32_16x16x128_f8f6f4(
          af, bf3, acc[i][3], 0, 0, 0, UNIT_SCALE, 0, UNIT_SCALE);
    }
    __syncthreads();  // all reads done before next STAGE overwrites
  }

  // ---- epilogue: C/D layout col = lane&15, row = quad*4 + reg (verified)
  int lbv[4];
#pragma unroll
  for (int j = 0; j < 4; j++) lbv[j] = lb[col0 + wn * 64 + j * 16 + l15];

#pragma unroll
  for (int i = 0; i < 4; i++) {
#pragma unroll
    for (int r = 0; r < 4; r++) {
      const int row = row0 + wm * 64 + i * 16 + q * 4 + r;
      const int lav = la[row];
      float sneg = 0.f, spos = 0.f;
#pragma unroll
      for (int j = 0; j < 4; j++) {
        float s = acc[i][j][r] * TEMP_INV;
        s = fminf(fmaxf(s, -50.f), 50.f);
        const float e = __expf(s);
        sneg += e;
        if (lav == lbv[j]) spos += e;
      }
#pragma unroll
      for (int m = 8; m >= 1; m >>= 1) {
        sneg += __shfl_xor(sneg, m, 16);
        spos += __shfl_xor(spos, m, 16);
      }
      if (l15 == 0) {
        atomicAdd(&neg_acc[row], sneg);
        atomicAdd(&pos_acc[row], spos);
      }
    }
  }
}

// ============================================================
// Kernel 3: loss = mean( log(neg) - log(max(pos,1e-8)) )
// ============================================================
__global__ __launch_bounds__(1024) void final_reduce(
    const float* __restrict__ pos, const float* __restrict__ neg,
    float* __restrict__ out, int N) {
  double local = 0.0;
  const int t = threadIdx.x;
  for (int i = t; i < N / 4; i += 1024) {
    const float4 p4 = ((const float4*)pos)[i];
    const float4 n4 = ((const float4*)neg)[i];
    local += (double)(logf(n4.x) - logf(fmaxf(p4.x, 1e-8f)));
    local += (double)(logf(n4.y) - logf(fmaxf(p4.y, 1e-8f)));
    local += (double)(logf(n4.z) - logf(fmaxf(p4.z, 1e-8f)));
    local += (double)(logf(n4.w) - logf(fmaxf(p4.w, 1e-8f)));
  }
#pragma unroll
  for (int m = 32; m >= 1; m >>= 1) local += __shfl_xor(local, m, 64);
  __shared__ double wsum[16];
  const int wave = t >> 6, lane = t & 63;
  if (lane == 0) wsum[wave] = local;
  __syncthreads();
  if (t == 0) {
    double tot = 0.0;
#pragma unroll
    for (int w = 0; w < 16; w++) tot += wsum[w];
    out[0] = (float)(tot / (double)N);
  }
}

extern "C" void kernel_launch(void* const* d_in, const int* in_sizes, int n_in,
                              void* d_out, int out_size, void* d_ws, size_t ws_size,
                              hipStream_t stream) {
  const float* fa = (const float*)d_in[0];
  const float* fb = (const float*)d_in[1];
  const int* la = (const int*)d_in[2];
  const int* lb = (const int*)d_in[3];

  const int D = 1024;
  const int N = in_sizes[0] / D;  // 8192
  const int M = in_sizes[1] / D;  // 8192

  unsigned char* nA = (unsigned char*)d_ws;
  unsigned char* nB = nA + (size_t)N * D;
  float* pos = (float*)(nB + (size_t)M * D);
  float* neg = pos + N;

  normalize_rows<<<N + M, 256, 0, stream>>>(fa, fb, nA, nB, pos, neg, N, D);

  dim3 grid(M / BN, N / BM);
  infonce_gemm<<<grid, 256, 0, stream>>>(nA, nB, la, lb, pos, neg, D);

  final_reduce<<<1, 1024, 0, stream>>>(pos, neg, (float*)d_out, N);
}